// Round 2
// baseline (562.838 us; speedup 1.0000x reference)
//
#include <hip/hip_runtime.h>

#define N_TOK 65536
#define DIM   256
#define K_CODES 1024
#define CB_OFF    16777216                    // N_TOK*DIM
#define PROBS_OFF (16777216 + 262144)
#define LOSS_OFF  (16777216 + 262144 + 1024)
#define TPB    128                            // tokens per block
#define CHUNK  32
#define NCHUNK 4

typedef float  f32x4  __attribute__((ext_vector_type(4)));
typedef short  s16x8  __attribute__((ext_vector_type(8)));

__device__ __forceinline__ unsigned short f32_to_bf16(float x) {
    unsigned u = __float_as_uint(x);
    unsigned r = (u + 0x7FFFu + ((u >> 16) & 1u)) >> 16;
    return (unsigned short)r;
}

// ---------------- K0: codebook -> bf16 scratch, c2[k] = ||c_k||^2 ----------------
__global__ __launch_bounds__(256) void k_prep(const float* __restrict__ cb,
                                              float* __restrict__ c2,
                                              unsigned short* __restrict__ cbf) {
    const int k = blockIdx.x;
    const int t = threadIdx.x;
    float x = cb[k * DIM + t];
    cbf[k * DIM + t] = f32_to_bf16(x);
    float v = x * x;
    #pragma unroll
    for (int off = 32; off; off >>= 1) v += __shfl_down(v, off, 64);
    __shared__ float sred[4];
    const int lane = t & 63, wv = t >> 6;
    if (lane == 0) sred[wv] = v;
    __syncthreads();
    if (t == 0) c2[k] = sred[0] + sred[1] + sred[2] + sred[3];
}

// ---------------- K1: fused distances + argmin + softmax + gather + loss ----------------
// Block: 256 threads (4 waves). 128 tokens/block in 4 chunks of 32.
// Wave w owns codes [256w, 256w+256). Per-chunk acc: 2 M x 16 N mfma tiles (128 VGPR).
// probs partial sums held in registers across chunks -> 1024 atomics/block at the end,
// spread over R replica arrays. Loss computed analytically: ||z-q||^2 = ||z||^2 + s_min.
__global__ __launch_bounds__(256, 2) void k_main(const float* __restrict__ z,
                                                 const float* __restrict__ cb,
                                                 const unsigned short* __restrict__ cbf,
                                                 const float* __restrict__ c2,
                                                 float* __restrict__ out_q,
                                                 float* __restrict__ probs_part,
                                                 float* __restrict__ lossR,
                                                 int repmask) {
    const int t   = threadIdx.x;
    const int w   = t >> 6;       // wave 0..3
    const int ln  = t & 63;       // lane
    const int q   = ln >> 4;      // quad
    const int l15 = ln & 15;
    const int k0  = w * 256;
    const int nbase = blockIdx.x * TPB;
    float* pp = probs_part + (blockIdx.x & repmask) * K_CODES;

    float c2v[16];
    #pragma unroll
    for (int nt = 0; nt < 16; nt++) c2v[nt] = c2[k0 + nt * 16 + l15];

    float ps[16];
    #pragma unroll
    for (int nt = 0; nt < 16; nt++) ps[nt] = 0.f;
    float lossreg = 0.f;

    __shared__ float redmin[4][32];
    __shared__ int   redidx[4][32];
    __shared__ float rede[4][32];
    __shared__ float z2s[32];
    __shared__ int   fidx[32];
    __shared__ float fU[32];

    const unsigned short* bbase = cbf + (k0 + l15) * DIM + q * 8;

    for (int c = 0; c < NCHUNK; c++) {
        const int n0 = nbase + c * CHUNK;

        f32x4 acc[2][16];
        #pragma unroll
        for (int m = 0; m < 2; m++)
            #pragma unroll
            for (int nt = 0; nt < 16; nt++) { f32x4 zr = {0.f, 0.f, 0.f, 0.f}; acc[m][nt] = zr; }

        float z2p[2] = {0.f, 0.f};

        // ---- K loop over d (8 steps of 32) ----
        #pragma unroll
        for (int ds = 0; ds < 8; ds++) {
            const int d0 = ds * 32;
            s16x8 afrag[2];
            #pragma unroll
            for (int m = 0; m < 2; m++) {
                const float* zp = z + (size_t)(n0 + m * 16 + l15) * DIM + d0 + q * 8;
                f32x4 z0 = *(const f32x4*)(zp);
                f32x4 z1 = *(const f32x4*)(zp + 4);
                z2p[m] += z0[0]*z0[0] + z0[1]*z0[1] + z0[2]*z0[2] + z0[3]*z0[3]
                        + z1[0]*z1[0] + z1[1]*z1[1] + z1[2]*z1[2] + z1[3]*z1[3];
                s16x8 a;
                a[0] = (short)f32_to_bf16(z0[0]); a[1] = (short)f32_to_bf16(z0[1]);
                a[2] = (short)f32_to_bf16(z0[2]); a[3] = (short)f32_to_bf16(z0[3]);
                a[4] = (short)f32_to_bf16(z1[0]); a[5] = (short)f32_to_bf16(z1[1]);
                a[6] = (short)f32_to_bf16(z1[2]); a[7] = (short)f32_to_bf16(z1[3]);
                afrag[m] = a;
            }
            #pragma unroll
            for (int nt = 0; nt < 16; nt++) {
                s16x8 b = *(const s16x8*)(bbase + nt * 16 * DIM + d0);
                acc[0][nt] = __builtin_amdgcn_mfma_f32_16x16x32_bf16(afrag[0], b, acc[0][nt], 0, 0, 0);
                acc[1][nt] = __builtin_amdgcn_mfma_f32_16x16x32_bf16(afrag[1], b, acc[1][nt], 0, 0, 0);
            }
        }

        // z2 per row: sum the 4 quads (lanes with same l15)
        #pragma unroll
        for (int m = 0; m < 2; m++) {
            z2p[m] += __shfl_xor(z2p[m], 16, 64);
            z2p[m] += __shfl_xor(z2p[m], 32, 64);
        }

        // ---- epilogue: s = c2 - 2*dot; local min/argmin/expsum; e -> acc ----
        float lmin[2][4], lesum[2][4]; int lidx[2][4];
        #pragma unroll
        for (int m = 0; m < 2; m++)
            #pragma unroll
            for (int v = 0; v < 4; v++) { lmin[m][v] = 3.4e38f; lidx[m][v] = 0x7fffffff; lesum[m][v] = 0.f; }

        #pragma unroll
        for (int m = 0; m < 2; m++)
            #pragma unroll
            for (int nt = 0; nt < 16; nt++) {
                const int col = k0 + nt * 16 + l15;
                #pragma unroll
                for (int v = 0; v < 4; v++) {
                    float s = c2v[nt] - 2.0f * acc[m][nt][v];
                    if (s < lmin[m][v]) { lmin[m][v] = s; lidx[m][v] = col; }
                    float e = __expf(-s);
                    acc[m][nt][v] = e;
                    lesum[m][v] += e;
                }
            }

        // cross-lane within quad group (16 lanes hold one row's 256-code slice)
        #pragma unroll
        for (int off = 1; off < 16; off <<= 1) {
            #pragma unroll
            for (int m = 0; m < 2; m++)
                #pragma unroll
                for (int v = 0; v < 4; v++) {
                    float omin = __shfl_xor(lmin[m][v], off, 64);
                    int   oidx = __shfl_xor(lidx[m][v], off, 64);
                    float oes  = __shfl_xor(lesum[m][v], off, 64);
                    if (omin < lmin[m][v] || (omin == lmin[m][v] && oidx < lidx[m][v])) {
                        lmin[m][v] = omin; lidx[m][v] = oidx;
                    }
                    lesum[m][v] += oes;
                }
        }

        // cross-wave combine through LDS
        if (l15 == 0) {
            #pragma unroll
            for (int m = 0; m < 2; m++)
                #pragma unroll
                for (int v = 0; v < 4; v++) {
                    const int r = m * 16 + q * 4 + v;
                    redmin[w][r] = lmin[m][v]; redidx[w][r] = lidx[m][v]; rede[w][r] = lesum[m][v];
                }
        }
        if (w == 0 && q == 0) { z2s[l15] = z2p[0]; z2s[16 + l15] = z2p[1]; }
        __syncthreads();
        if (t < 32) {
            float bm = redmin[0][t]; int bi = redidx[0][t];
            float U  = rede[0][t];
            #pragma unroll
            for (int ww = 1; ww < 4; ww++) {
                float m2 = redmin[ww][t]; int i2 = redidx[ww][t];
                if (m2 < bm || (m2 == bm && i2 < bi)) { bm = m2; bi = i2; }
                U += rede[ww][t];
            }
            fidx[t] = bi; fU[t] = U;
            lossreg += z2s[t] + bm;   // ||z-q||^2 = ||z||^2 + s_min
        }
        __syncthreads();

        // probs: ps += e / U  (register accumulation across chunks)
        #pragma unroll
        for (int m = 0; m < 2; m++)
            #pragma unroll
            for (int v = 0; v < 4; v++) {
                const float invU = 1.0f / fU[m * 16 + q * 4 + v];
                #pragma unroll
                for (int nt = 0; nt < 16; nt++) ps[nt] += acc[m][nt][v] * invU;
            }

        // quantized gather + store: wave w handles rows [8w, 8w+8)
        #pragma unroll
        for (int i = 0; i < 8; i++) {
            const int r  = w * 8 + i;
            const int am = fidx[r];
            f32x4 qv = *(const f32x4*)(cb + (size_t)am * DIM + ln * 4);
            *(f32x4*)(out_q + (size_t)(n0 + r) * DIM + ln * 4) = qv;
        }
        __syncthreads();   // protect LDS reuse next chunk
    }

    // ---- final: probs atomics (once per block) ----
    #pragma unroll
    for (int nt = 0; nt < 16; nt++) {
        ps[nt] += __shfl_xor(ps[nt], 16, 64);
        ps[nt] += __shfl_xor(ps[nt], 32, 64);
    }
    if (q == 0) {
        #pragma unroll
        for (int nt = 0; nt < 16; nt++)
            atomicAdd(&pp[k0 + nt * 16 + l15], ps[nt]);
    }
    // ---- loss: one atomic per block, spread over 64 slots ----
    if (w == 0) {
        #pragma unroll
        for (int off = 32; off; off >>= 1) lossreg += __shfl_down(lossreg, off, 64);
        if (ln == 0) atomicAdd(&lossR[blockIdx.x & 63], lossreg);
    }
}

// ---------------- K2: codebook copy, probs reduce+mean+clip, vq_loss ----------------
__global__ __launch_bounds__(256) void k_fin(const float* __restrict__ cb,
                                             const float* __restrict__ probs_part,
                                             const float* __restrict__ lossR,
                                             float* __restrict__ out,
                                             int R, int nLoss) {
    const int g = blockIdx.x * 256 + threadIdx.x;   // 0 .. 262143
    out[CB_OFF + g] = cb[g];
    if (g < K_CODES) {
        float acc = 0.f;
        for (int r = 0; r < R; r++) acc += probs_part[r * K_CODES + g];
        float p = acc * (1.0f / 65536.0f);
        p = fminf(fmaxf(p, 0.001f), 0.999f);
        out[PROBS_OFF + g] = p;
    }
    if (g == 0) {
        float ls = 0.f;
        for (int r = 0; r < nLoss; r++) ls += lossR[r];
        // vq_loss = (1 + 0.25) * 1024 * sum_sq / (65536*256)
        out[LOSS_OFF] = ls * (1280.0f / 16777216.0f);
    }
}

extern "C" void kernel_launch(void* const* d_in, const int* in_sizes, int n_in,
                              void* d_out, int out_size, void* d_ws, size_t ws_size,
                              hipStream_t stream) {
    (void)in_sizes; (void)n_in; (void)out_size;
    const float* z  = (const float*)d_in[0];
    const float* cb = (const float*)d_in[1];
    float* out = (float*)d_out;

    float* c2 = (float*)d_ws;                 // 1024 floats (always fits: round-1 used 8.2 KB)
    // bf16 codebook scratch lives in d_out's codebook region; k_fin rewrites it with fp32.
    unsigned short* cbf = (unsigned short*)(out + CB_OFF);

    // Accumulator placement: prefer 64 probs replicas + 64 loss slots in ws.
    const size_t need64 = (size_t)(1024 + 64 + 64 * 1024) * 4;
    float *probs_part, *lossR;
    int R, nLoss;
    if (ws_size >= need64) {
        lossR      = c2 + 1024;               // 64 floats
        probs_part = lossR + 64;              // 64*1024 floats
        R = 64; nLoss = 64;
        hipMemsetAsync(lossR, 0, (size_t)(64 + 64 * 1024) * 4, stream);
    } else {
        // fallback: single accumulators in d_out's probs/loss region
        probs_part = out + PROBS_OFF;
        lossR      = out + LOSS_OFF;
        R = 1; nLoss = 1;
        hipMemsetAsync(out + PROBS_OFF, 0, (size_t)(K_CODES + 1) * 4, stream);
    }

    k_prep<<<dim3(K_CODES), dim3(256), 0, stream>>>(cb, c2, cbf);
    k_main<<<dim3(N_TOK / TPB), dim3(256), 0, stream>>>(z, cb, cbf, c2, out, probs_part,
                                                        lossR, (R == 64) ? 63 : 0);
    k_fin<<<dim3(262144 / 256), dim3(256), 0, stream>>>(cb, probs_part, lossR, out, R, nLoss);
}

// Round 3
// 316.430 us; speedup vs baseline: 1.7787x; 1.7787x over previous
//
#include <hip/hip_runtime.h>

#define N_TOK 65536
#define DIM   256
#define K_CODES 1024
#define CB_OFF    16777216                    // N_TOK*DIM
#define PROBS_OFF (16777216 + 262144)
#define LOSS_OFF  (16777216 + 262144 + 1024)

typedef float  f32x4  __attribute__((ext_vector_type(4)));
typedef short  s16x8  __attribute__((ext_vector_type(8)));

__device__ __forceinline__ unsigned short f32_to_bf16(float x) {
    unsigned u = __float_as_uint(x);
    unsigned r = (u + 0x7FFFu + ((u >> 16) & 1u)) >> 16;
    return (unsigned short)r;
}

// ---------------- K0: codebook -> bf16 scratch, c2[k] = ||c_k||^2 ----------------
__global__ __launch_bounds__(256) void k_prep(const float* __restrict__ cb,
                                              float* __restrict__ c2,
                                              unsigned short* __restrict__ cbf) {
    const int k = blockIdx.x;
    const int t = threadIdx.x;
    float x = cb[k * DIM + t];
    cbf[k * DIM + t] = f32_to_bf16(x);
    float v = x * x;
    #pragma unroll
    for (int off = 32; off; off >>= 1) v += __shfl_down(v, off, 64);
    __shared__ float sred[4];
    const int lane = t & 63, wv = t >> 6;
    if (lane == 0) sred[wv] = v;
    __syncthreads();
    if (t == 0) c2[k] = sred[0] + sred[1] + sred[2] + sred[3];
}

// ---------------- K1: fused distances + argmin + softmax + gather + loss ----------------
// 32 tokens/block, grid 2048 (R1 structure: short-lived blocks keep cbf L2-hot).
// Wave w owns codes [256w, 256w+256). acc: 2 M x 16 N mfma tiles (128 acc regs).
// Probs atomics spread over 64 replica arrays, issued by all 4 quads in parallel.
// Loss analytic: ||z-q||^2 = ||z||^2 + s_min  (no second z read, no gather diff).
__global__ __launch_bounds__(256, 2) void k_main(const float* __restrict__ z,
                                                 const float* __restrict__ cb,
                                                 const unsigned short* __restrict__ cbf,
                                                 const float* __restrict__ c2,
                                                 float* __restrict__ out_q,
                                                 float* __restrict__ probs_part,
                                                 float* __restrict__ lossR,
                                                 int repmask) {
    const int t   = threadIdx.x;
    const int w   = t >> 6;       // wave 0..3
    const int ln  = t & 63;       // lane
    const int q   = ln >> 4;      // quad
    const int l15 = ln & 15;
    const int k0  = w * 256;
    const int n0  = blockIdx.x * 32;
    float* pp = probs_part + (blockIdx.x & repmask) * K_CODES;

    f32x4 acc[2][16];
    #pragma unroll
    for (int m = 0; m < 2; m++)
        #pragma unroll
        for (int nt = 0; nt < 16; nt++) { f32x4 zr = {0.f, 0.f, 0.f, 0.f}; acc[m][nt] = zr; }

    float z2p[2] = {0.f, 0.f};
    const unsigned short* bbase = cbf + (k0 + l15) * DIM + q * 8;

    // ---- K loop over d (8 steps of 32) ----
    #pragma unroll
    for (int ds = 0; ds < 8; ds++) {
        const int d0 = ds * 32;
        s16x8 afrag[2];
        #pragma unroll
        for (int m = 0; m < 2; m++) {
            const float* zp = z + (size_t)(n0 + m * 16 + l15) * DIM + d0 + q * 8;
            f32x4 z0 = *(const f32x4*)(zp);
            f32x4 z1 = *(const f32x4*)(zp + 4);
            z2p[m] += z0[0]*z0[0] + z0[1]*z0[1] + z0[2]*z0[2] + z0[3]*z0[3]
                    + z1[0]*z1[0] + z1[1]*z1[1] + z1[2]*z1[2] + z1[3]*z1[3];
            s16x8 a;
            a[0] = (short)f32_to_bf16(z0[0]); a[1] = (short)f32_to_bf16(z0[1]);
            a[2] = (short)f32_to_bf16(z0[2]); a[3] = (short)f32_to_bf16(z0[3]);
            a[4] = (short)f32_to_bf16(z1[0]); a[5] = (short)f32_to_bf16(z1[1]);
            a[6] = (short)f32_to_bf16(z1[2]); a[7] = (short)f32_to_bf16(z1[3]);
            afrag[m] = a;
        }
        #pragma unroll
        for (int nt = 0; nt < 16; nt++) {
            s16x8 b = *(const s16x8*)(bbase + nt * 16 * DIM + d0);
            acc[0][nt] = __builtin_amdgcn_mfma_f32_16x16x32_bf16(afrag[0], b, acc[0][nt], 0, 0, 0);
            acc[1][nt] = __builtin_amdgcn_mfma_f32_16x16x32_bf16(afrag[1], b, acc[1][nt], 0, 0, 0);
        }
    }

    // z2 per row: sum the 4 quads (lanes with same l15)
    #pragma unroll
    for (int m = 0; m < 2; m++) {
        z2p[m] += __shfl_xor(z2p[m], 16, 64);
        z2p[m] += __shfl_xor(z2p[m], 32, 64);
    }

    // ---- epilogue: s = c2 - 2*dot; local min/argmin/expsum; e -> acc ----
    float c2v[16];
    #pragma unroll
    for (int nt = 0; nt < 16; nt++) c2v[nt] = c2[k0 + nt * 16 + l15];

    float lmin[2][4], lesum[2][4]; int lidx[2][4];
    #pragma unroll
    for (int m = 0; m < 2; m++)
        #pragma unroll
        for (int v = 0; v < 4; v++) { lmin[m][v] = 3.4e38f; lidx[m][v] = 0x7fffffff; lesum[m][v] = 0.f; }

    #pragma unroll
    for (int m = 0; m < 2; m++)
        #pragma unroll
        for (int nt = 0; nt < 16; nt++) {
            const int col = k0 + nt * 16 + l15;
            #pragma unroll
            for (int v = 0; v < 4; v++) {
                float s = c2v[nt] - 2.0f * acc[m][nt][v];
                if (s < lmin[m][v]) { lmin[m][v] = s; lidx[m][v] = col; }
                float e = __expf(-s);
                acc[m][nt][v] = e;
                lesum[m][v] += e;
            }
        }

    // cross-lane within quad group (16 lanes hold one row's 256-code slice)
    #pragma unroll
    for (int off = 1; off < 16; off <<= 1) {
        #pragma unroll
        for (int m = 0; m < 2; m++)
            #pragma unroll
            for (int v = 0; v < 4; v++) {
                float omin = __shfl_xor(lmin[m][v], off, 64);
                int   oidx = __shfl_xor(lidx[m][v], off, 64);
                float oes  = __shfl_xor(lesum[m][v], off, 64);
                if (omin < lmin[m][v] || (omin == lmin[m][v] && oidx < lidx[m][v])) {
                    lmin[m][v] = omin; lidx[m][v] = oidx;
                }
                lesum[m][v] += oes;
            }
    }

    // cross-wave combine through LDS
    __shared__ float redmin[4][32];
    __shared__ int   redidx[4][32];
    __shared__ float rede[4][32];
    __shared__ float z2s[32];
    __shared__ int   fidx[32];
    __shared__ float fU[32];
    if (l15 == 0) {
        #pragma unroll
        for (int m = 0; m < 2; m++)
            #pragma unroll
            for (int v = 0; v < 4; v++) {
                const int r = m * 16 + q * 4 + v;
                redmin[w][r] = lmin[m][v]; redidx[w][r] = lidx[m][v]; rede[w][r] = lesum[m][v];
            }
    }
    if (w == 0 && q == 0) { z2s[l15] = z2p[0]; z2s[16 + l15] = z2p[1]; }
    __syncthreads();
    float lossreg = 0.f;
    if (t < 32) {
        float bm = redmin[0][t]; int bi = redidx[0][t];
        float U  = rede[0][t];
        #pragma unroll
        for (int ww = 1; ww < 4; ww++) {
            float m2 = redmin[ww][t]; int i2 = redidx[ww][t];
            if (m2 < bm || (m2 == bm && i2 < bi)) { bm = m2; bi = i2; }
            U += rede[ww][t];
        }
        fidx[t] = bi; fU[t] = U;
        lossreg = z2s[t] + bm;   // ||z-q||^2 = ||z||^2 + s_min
    }
    __syncthreads();

    // probs: ps = sum over the block's 32 rows of e/U, per code column
    float ps[16];
    #pragma unroll
    for (int nt = 0; nt < 16; nt++) ps[nt] = 0.f;
    #pragma unroll
    for (int m = 0; m < 2; m++)
        #pragma unroll
        for (int v = 0; v < 4; v++) {
            const float invU = 1.0f / fU[m * 16 + q * 4 + v];
            #pragma unroll
            for (int nt = 0; nt < 16; nt++) ps[nt] += acc[m][nt][v] * invU;
        }
    #pragma unroll
    for (int nt = 0; nt < 16; nt++) {
        ps[nt] += __shfl_xor(ps[nt], 16, 64);
        ps[nt] += __shfl_xor(ps[nt], 32, 64);
    }
    // quad q issues the atomics for nt = 4q .. 4q+3 (4 per lane, quads in parallel)
    #pragma unroll
    for (int j = 0; j < 4; j++) {
        const int nt = q * 4 + j;
        atomicAdd(&pp[k0 + nt * 16 + l15], ps[nt]);
    }

    // quantized gather + store: wave w handles rows [8w, 8w+8)
    #pragma unroll
    for (int i = 0; i < 8; i++) {
        const int r  = w * 8 + i;
        const int am = fidx[r];
        f32x4 qv = *(const f32x4*)(cb + (size_t)am * DIM + ln * 4);
        *(f32x4*)(out_q + (size_t)(n0 + r) * DIM + ln * 4) = qv;
    }

    // loss: one atomic per block, spread over 64 slots
    if (w == 0) {
        #pragma unroll
        for (int off = 32; off; off >>= 1) lossreg += __shfl_down(lossreg, off, 64);
        if (ln == 0) atomicAdd(&lossR[blockIdx.x & 63], lossreg);
    }
}

// ---------------- K2: codebook copy, probs reduce+mean+clip, vq_loss ----------------
__global__ __launch_bounds__(256) void k_fin(const float* __restrict__ cb,
                                             const float* __restrict__ probs_part,
                                             const float* __restrict__ lossR,
                                             float* __restrict__ out,
                                             int R, int nLoss) {
    const int g = blockIdx.x * 256 + threadIdx.x;   // 0 .. 262143
    out[CB_OFF + g] = cb[g];
    if (g < K_CODES) {
        float acc = 0.f;
        for (int r = 0; r < R; r++) acc += probs_part[r * K_CODES + g];
        float p = acc * (1.0f / 65536.0f);
        p = fminf(fmaxf(p, 0.001f), 0.999f);
        out[PROBS_OFF + g] = p;
    }
    if (g == 0) {
        float ls = 0.f;
        for (int r = 0; r < nLoss; r++) ls += lossR[r];
        // vq_loss = (1 + 0.25) * 1024 * sum_sq / (65536*256)
        out[LOSS_OFF] = ls * (1280.0f / 16777216.0f);
    }
}

extern "C" void kernel_launch(void* const* d_in, const int* in_sizes, int n_in,
                              void* d_out, int out_size, void* d_ws, size_t ws_size,
                              hipStream_t stream) {
    (void)in_sizes; (void)n_in; (void)out_size;
    const float* z  = (const float*)d_in[0];
    const float* cb = (const float*)d_in[1];
    float* out = (float*)d_out;

    float* c2 = (float*)d_ws;                 // 1024 floats
    // bf16 codebook scratch lives in d_out's codebook region; k_fin rewrites it with fp32.
    unsigned short* cbf = (unsigned short*)(out + CB_OFF);

    // Accumulator placement: as many probs replicas as ws allows (pow2, <=64).
    float *probs_part, *lossR;
    int R = 64, nLoss;
    while (R > 1 && ws_size < (size_t)(1024 + 64 + R * 1024) * 4) R >>= 1;
    if (ws_size >= (size_t)(1024 + 64 + R * 1024) * 4) {
        lossR      = c2 + 1024;               // 64 floats
        probs_part = lossR + 64;              // R*1024 floats
        nLoss = 64;
        hipMemsetAsync(lossR, 0, (size_t)(64 + R * 1024) * 4, stream);
    } else {
        probs_part = out + PROBS_OFF;
        lossR      = out + LOSS_OFF;
        R = 1; nLoss = 1;
        hipMemsetAsync(out + PROBS_OFF, 0, (size_t)(K_CODES + 1) * 4, stream);
    }

    k_prep<<<dim3(K_CODES), dim3(256), 0, stream>>>(cb, c2, cbf);
    k_main<<<dim3(N_TOK / 32), dim3(256), 0, stream>>>(z, cb, cbf, c2, out, probs_part,
                                                       lossR, R - 1);
    k_fin<<<dim3(262144 / 256), dim3(256), 0, stream>>>(cb, probs_part, lossR, out, R, nLoss);
}

// Round 4
// 218.543 us; speedup vs baseline: 2.5754x; 1.4479x over previous
//
#include <hip/hip_runtime.h>

#define N_TOK 65536
#define DIM   256
#define K_CODES 1024
#define CB_OFF    16777216                    // N_TOK*DIM
#define PROBS_OFF (16777216 + 262144)
#define LOSS_OFF  (16777216 + 262144 + 1024)

typedef float  f32x4  __attribute__((ext_vector_type(4)));
typedef short  s16x8  __attribute__((ext_vector_type(8)));

__device__ __forceinline__ unsigned short f32_to_bf16(float x) {
    unsigned u = __float_as_uint(x);
    unsigned r = (u + 0x7FFFu + ((u >> 16) & 1u)) >> 16;
    return (unsigned short)r;
}

// ---------------- K0: codebook -> bf16 frag-layout scratch + c2 ----------------
// Block g (64 blocks, 512 thr) handles code group g (16 codes).
// Wave wv handles K-step ds=wv: lane ln produces the s16x8 B-fragment
//   element j = cb[(g*16 + (ln&15))*256 + wv*32 + (ln>>4)*8 + j]
// stored contiguously at cbf[(g*8 + wv)*1024 + ln*8]  -> k_main B loads are
// fully-coalesced 1KiB global_load_dwordx4.
__global__ __launch_bounds__(512) void k_prep(const float* __restrict__ cb,
                                              float* __restrict__ c2,
                                              unsigned short* __restrict__ cbf) {
    const int g  = blockIdx.x;
    const int t  = threadIdx.x;
    const int wv = t >> 6;
    const int ln = t & 63;
    const int l15 = ln & 15, q = ln >> 4;

    const float* zp = cb + (size_t)(g * 16 + l15) * DIM + wv * 32 + q * 8;
    f32x4 z0 = *(const f32x4*)(zp);
    f32x4 z1 = *(const f32x4*)(zp + 4);
    s16x8 a;
    a[0] = (short)f32_to_bf16(z0[0]); a[1] = (short)f32_to_bf16(z0[1]);
    a[2] = (short)f32_to_bf16(z0[2]); a[3] = (short)f32_to_bf16(z0[3]);
    a[4] = (short)f32_to_bf16(z1[0]); a[5] = (short)f32_to_bf16(z1[1]);
    a[6] = (short)f32_to_bf16(z1[2]); a[7] = (short)f32_to_bf16(z1[3]);
    *(s16x8*)(cbf + (size_t)(g * 8 + wv) * 1024 + ln * 8) = a;

    float s = z0[0]*z0[0] + z0[1]*z0[1] + z0[2]*z0[2] + z0[3]*z0[3]
            + z1[0]*z1[0] + z1[1]*z1[1] + z1[2]*z1[2] + z1[3]*z1[3];
    s += __shfl_xor(s, 16, 64);
    s += __shfl_xor(s, 32, 64);   // lanes 0..15 hold this wave's 32-dim partial per code
    __shared__ float c2p[8][16];
    if (q == 0) c2p[wv][l15] = s;
    __syncthreads();
    if (t < 16) {
        float acc = 0.f;
        #pragma unroll
        for (int ww = 0; ww < 8; ww++) acc += c2p[ww][t];
        c2[g * 16 + t] = acc;
    }
}

// ---------------- K1: fused distances + argmin + softmax + gather + loss ----------------
// 512 threads (8 waves), 32 tokens/block, grid 2048. Wave w owns codes [128w,128w+128).
// A (32x256 bf16, frag order) staged once in LDS; B loads coalesced from frag-layout cbf.
// acc: 2 M x 8 N tiles = 64 AGPR -> target 4 waves/SIMD.
__global__ __launch_bounds__(512, 4) void k_main(const float* __restrict__ z,
                                                 const float* __restrict__ cb,
                                                 const unsigned short* __restrict__ cbf,
                                                 const float* __restrict__ c2,
                                                 float* __restrict__ out_q,
                                                 float* __restrict__ probs_part,
                                                 float* __restrict__ lossR,
                                                 int repmask) {
    const int t   = threadIdx.x;
    const int w   = t >> 6;       // wave 0..7
    const int ln  = t & 63;
    const int q   = ln >> 4;
    const int l15 = ln & 15;
    const int k0  = w * 128;
    const int n0  = blockIdx.x * 32;
    float* pp = probs_part + (blockIdx.x & repmask) * K_CODES;

    __shared__ unsigned short a_lds[16 * 64 * 8];   // 16 KB: frag f=(m*8+ds)*64+ln at a_lds[f*8]
    __shared__ float z2s[32];
    __shared__ float redmin[8][32];
    __shared__ int   redidx[8][32];
    __shared__ float rede[8][32];
    __shared__ int   fidx[32];
    __shared__ float fU[32];

    if (t < 32) z2s[t] = 0.f;
    __syncthreads();

    // ---- phase 0: cooperative A fill (fp32 -> bf16, fragment order) + z2 ----
    #pragma unroll
    for (int rep = 0; rep < 2; rep++) {
        const int f   = t + rep * 512;
        const int md  = f >> 6;            // m*8+ds
        const int fl  = f & 63;
        const int row = ((md >> 3) * 16) + (fl & 15);
        const int dim = (md & 7) * 32 + (fl >> 4) * 8;
        const float* zp = z + (size_t)(n0 + row) * DIM + dim;
        f32x4 z0 = *(const f32x4*)(zp);
        f32x4 z1 = *(const f32x4*)(zp + 4);
        s16x8 a;
        a[0] = (short)f32_to_bf16(z0[0]); a[1] = (short)f32_to_bf16(z0[1]);
        a[2] = (short)f32_to_bf16(z0[2]); a[3] = (short)f32_to_bf16(z0[3]);
        a[4] = (short)f32_to_bf16(z1[0]); a[5] = (short)f32_to_bf16(z1[1]);
        a[6] = (short)f32_to_bf16(z1[2]); a[7] = (short)f32_to_bf16(z1[3]);
        *(s16x8*)(a_lds + (size_t)f * 8) = a;
        float s = z0[0]*z0[0] + z0[1]*z0[1] + z0[2]*z0[2] + z0[3]*z0[3]
                + z1[0]*z1[0] + z1[1]*z1[1] + z1[2]*z1[2] + z1[3]*z1[3];
        atomicAdd(&z2s[row], s);
    }
    __syncthreads();

    // ---- K loop: 8 steps of 32 dims ----
    f32x4 acc[2][8];
    #pragma unroll
    for (int m = 0; m < 2; m++)
        #pragma unroll
        for (int nt = 0; nt < 8; nt++) { f32x4 zr = {0.f, 0.f, 0.f, 0.f}; acc[m][nt] = zr; }

    const unsigned short* bb = cbf + (size_t)(w * 8) * 8 * 1024 + ln * 8;

    #pragma unroll
    for (int ds = 0; ds < 8; ds++) {
        s16x8 a0 = *(const s16x8*)(a_lds + (size_t)((0 * 8 + ds) * 64 + ln) * 8);
        s16x8 a1 = *(const s16x8*)(a_lds + (size_t)((1 * 8 + ds) * 64 + ln) * 8);
        #pragma unroll
        for (int nt = 0; nt < 8; nt++) {
            s16x8 b = *(const s16x8*)(bb + (size_t)(nt * 8 + ds) * 1024);
            acc[0][nt] = __builtin_amdgcn_mfma_f32_16x16x32_bf16(a0, b, acc[0][nt], 0, 0, 0);
            acc[1][nt] = __builtin_amdgcn_mfma_f32_16x16x32_bf16(a1, b, acc[1][nt], 0, 0, 0);
        }
    }

    // ---- epilogue: s = c2 - 2*dot; local min/argmin/expsum; e -> acc ----
    float c2v[8];
    #pragma unroll
    for (int nt = 0; nt < 8; nt++) c2v[nt] = c2[k0 + nt * 16 + l15];

    float lmin[2][4], lesum[2][4]; int lidx[2][4];
    #pragma unroll
    for (int m = 0; m < 2; m++)
        #pragma unroll
        for (int v = 0; v < 4; v++) { lmin[m][v] = 3.4e38f; lidx[m][v] = 0x7fffffff; lesum[m][v] = 0.f; }

    #pragma unroll
    for (int m = 0; m < 2; m++)
        #pragma unroll
        for (int nt = 0; nt < 8; nt++) {
            const int col = k0 + nt * 16 + l15;
            #pragma unroll
            for (int v = 0; v < 4; v++) {
                float s = c2v[nt] - 2.0f * acc[m][nt][v];
                if (s < lmin[m][v]) { lmin[m][v] = s; lidx[m][v] = col; }
                float e = __expf(-s);
                acc[m][nt][v] = e;
                lesum[m][v] += e;
            }
        }

    // cross-lane within quad group (16 lanes hold one row's 128-code slice)
    #pragma unroll
    for (int off = 1; off < 16; off <<= 1) {
        #pragma unroll
        for (int m = 0; m < 2; m++)
            #pragma unroll
            for (int v = 0; v < 4; v++) {
                float omin = __shfl_xor(lmin[m][v], off, 64);
                int   oidx = __shfl_xor(lidx[m][v], off, 64);
                float oes  = __shfl_xor(lesum[m][v], off, 64);
                if (omin < lmin[m][v] || (omin == lmin[m][v] && oidx < lidx[m][v])) {
                    lmin[m][v] = omin; lidx[m][v] = oidx;
                }
                lesum[m][v] += oes;
            }
    }

    // cross-wave combine (8 waves) through LDS
    if (l15 == 0) {
        #pragma unroll
        for (int m = 0; m < 2; m++)
            #pragma unroll
            for (int v = 0; v < 4; v++) {
                const int r = m * 16 + q * 4 + v;
                redmin[w][r] = lmin[m][v]; redidx[w][r] = lidx[m][v]; rede[w][r] = lesum[m][v];
            }
    }
    __syncthreads();
    float lossreg = 0.f;
    if (t < 32) {
        float bm = redmin[0][t]; int bi = redidx[0][t];
        float U  = rede[0][t];
        #pragma unroll
        for (int ww = 1; ww < 8; ww++) {
            float m2 = redmin[ww][t]; int i2 = redidx[ww][t];
            if (m2 < bm || (m2 == bm && i2 < bi)) { bm = m2; bi = i2; }
            U += rede[ww][t];
        }
        fidx[t] = bi; fU[t] = U;
        lossreg = z2s[t] + bm;   // ||z-q||^2 = ||z||^2 + s_min
    }
    __syncthreads();

    // probs: column sums of e/U over the block's 32 rows
    float ps[8];
    #pragma unroll
    for (int nt = 0; nt < 8; nt++) ps[nt] = 0.f;
    #pragma unroll
    for (int m = 0; m < 2; m++)
        #pragma unroll
        for (int v = 0; v < 4; v++) {
            const float invU = 1.0f / fU[m * 16 + q * 4 + v];
            #pragma unroll
            for (int nt = 0; nt < 8; nt++) ps[nt] += acc[m][nt][v] * invU;
        }
    #pragma unroll
    for (int nt = 0; nt < 8; nt++) {
        ps[nt] += __shfl_xor(ps[nt], 16, 64);
        ps[nt] += __shfl_xor(ps[nt], 32, 64);
    }
    // quad q issues atomics for nt = 2q, 2q+1 (2 per lane, quads in parallel)
    #pragma unroll
    for (int j = 0; j < 2; j++) {
        const int nt = q * 2 + j;
        atomicAdd(&pp[k0 + nt * 16 + l15], ps[nt]);
    }

    // quantized gather + store: wave w handles rows [4w, 4w+4)
    #pragma unroll
    for (int i = 0; i < 4; i++) {
        const int r  = w * 4 + i;
        const int am = fidx[r];
        f32x4 qv = *(const f32x4*)(cb + (size_t)am * DIM + ln * 4);
        *(f32x4*)(out_q + (size_t)(n0 + r) * DIM + ln * 4) = qv;
    }

    // loss: one atomic per block, spread over 64 slots
    if (w == 0) {
        #pragma unroll
        for (int off = 32; off; off >>= 1) lossreg += __shfl_down(lossreg, off, 64);
        if (ln == 0) atomicAdd(&lossR[blockIdx.x & 63], lossreg);
    }
}

// ---------------- K2: codebook copy, probs reduce+mean+clip, vq_loss ----------------
__global__ __launch_bounds__(256) void k_fin(const float* __restrict__ cb,
                                             const float* __restrict__ probs_part,
                                             const float* __restrict__ lossR,
                                             float* __restrict__ out,
                                             int R, int nLoss) {
    const int g = blockIdx.x * 256 + threadIdx.x;   // 0 .. 262143
    out[CB_OFF + g] = cb[g];
    if (g < K_CODES) {
        float acc = 0.f;
        for (int r = 0; r < R; r++) acc += probs_part[r * K_CODES + g];
        float p = acc * (1.0f / 65536.0f);
        p = fminf(fmaxf(p, 0.001f), 0.999f);
        out[PROBS_OFF + g] = p;
    }
    if (g == 0) {
        float ls = 0.f;
        for (int r = 0; r < nLoss; r++) ls += lossR[r];
        // vq_loss = (1 + 0.25) * 1024 * sum_sq / (65536*256)
        out[LOSS_OFF] = ls * (1280.0f / 16777216.0f);
    }
}

extern "C" void kernel_launch(void* const* d_in, const int* in_sizes, int n_in,
                              void* d_out, int out_size, void* d_ws, size_t ws_size,
                              hipStream_t stream) {
    (void)in_sizes; (void)n_in; (void)out_size;
    const float* z  = (const float*)d_in[0];
    const float* cb = (const float*)d_in[1];
    float* out = (float*)d_out;

    float* c2 = (float*)d_ws;                 // 1024 floats
    // bf16 frag-layout codebook scratch lives in d_out's codebook region (512 KB of the
    // 1 MB region); k_fin rewrites it with the fp32 copy afterwards.
    unsigned short* cbf = (unsigned short*)(out + CB_OFF);

    // Accumulator placement: as many probs replicas as ws allows (pow2, <=64).
    float *probs_part, *lossR;
    int R = 64, nLoss;
    while (R > 1 && ws_size < (size_t)(1024 + 64 + R * 1024) * 4) R >>= 1;
    if (ws_size >= (size_t)(1024 + 64 + R * 1024) * 4) {
        lossR      = c2 + 1024;               // 64 floats
        probs_part = lossR + 64;              // R*1024 floats
        nLoss = 64;
        hipMemsetAsync(lossR, 0, (size_t)(64 + R * 1024) * 4, stream);
    } else {
        probs_part = out + PROBS_OFF;
        lossR      = out + LOSS_OFF;
        R = 1; nLoss = 1;
        hipMemsetAsync(out + PROBS_OFF, 0, (size_t)(K_CODES + 1) * 4, stream);
    }

    k_prep<<<dim3(K_CODES / 16), dim3(512), 0, stream>>>(cb, c2, cbf);
    k_main<<<dim3(N_TOK / 32), dim3(512), 0, stream>>>(z, cb, cbf, c2, out, probs_part,
                                                       lossR, R - 1);
    k_fin<<<dim3(262144 / 256), dim3(256), 0, stream>>>(cb, probs_part, lossR, out, R, nLoss);
}

// Round 5
// 208.072 us; speedup vs baseline: 2.7050x; 1.0503x over previous
//
#include <hip/hip_runtime.h>

#define N_TOK 65536
#define DIM   256
#define K_CODES 1024
#define CB_OFF    16777216                    // N_TOK*DIM
#define PROBS_OFF (16777216 + 262144)
#define LOSS_OFF  (16777216 + 262144 + 1024)
#define TM 64                                 // tokens per k_main block

typedef float  f32x4  __attribute__((ext_vector_type(4)));
typedef short  s16x8  __attribute__((ext_vector_type(8)));

__device__ __forceinline__ unsigned short f32_to_bf16(float x) {
    unsigned u = __float_as_uint(x);
    unsigned r = (u + 0x7FFFu + ((u >> 16) & 1u)) >> 16;
    return (unsigned short)r;
}
// monotone uint key for float MAX-reduction (no NaNs here)
__device__ __forceinline__ unsigned fkey(float a) {
    unsigned u = __float_as_uint(a);
    unsigned m = (unsigned)(((int)u) >> 31);
    return u ^ (m | 0x80000000u);
}
__device__ __forceinline__ float fkey_inv(unsigned k) {
    unsigned u = (k & 0x80000000u) ? (k ^ 0x80000000u) : ~k;
    return __uint_as_float(u);
}

// ---------------- K0: codebook -> bf16 frag-layout scratch + c2 + zero accs (+fp32 copy) ----
// Block g (64 blocks, 512 thr) handles code group g (16 codes), exactly as round 4.
// Extra duties: zero probs_part[0..zcount) and lossR[0..64); if docopy, write the fp32
// codebook into out (cbf lives in ws in that case).
__global__ __launch_bounds__(512) void k_prep(const float* __restrict__ cb,
                                              float* __restrict__ c2,
                                              unsigned short* __restrict__ cbf,
                                              float* __restrict__ probs_part,
                                              float* __restrict__ lossR,
                                              float* __restrict__ outcb,
                                              int zcount, int nloss, int docopy) {
    const int g  = blockIdx.x;
    const int t  = threadIdx.x;
    const int wv = t >> 6;
    const int ln = t & 63;
    const int l15 = ln & 15, q = ln >> 4;

    const float* zp = cb + (size_t)(g * 16 + l15) * DIM + wv * 32 + q * 8;
    f32x4 z0 = *(const f32x4*)(zp);
    f32x4 z1 = *(const f32x4*)(zp + 4);
    s16x8 a;
    a[0] = (short)f32_to_bf16(z0[0]); a[1] = (short)f32_to_bf16(z0[1]);
    a[2] = (short)f32_to_bf16(z0[2]); a[3] = (short)f32_to_bf16(z0[3]);
    a[4] = (short)f32_to_bf16(z1[0]); a[5] = (short)f32_to_bf16(z1[1]);
    a[6] = (short)f32_to_bf16(z1[2]); a[7] = (short)f32_to_bf16(z1[3]);
    *(s16x8*)(cbf + (size_t)(g * 8 + wv) * 1024 + ln * 8) = a;

    float s = z0[0]*z0[0] + z0[1]*z0[1] + z0[2]*z0[2] + z0[3]*z0[3]
            + z1[0]*z1[0] + z1[1]*z1[1] + z1[2]*z1[2] + z1[3]*z1[3];
    s += __shfl_xor(s, 16, 64);
    s += __shfl_xor(s, 32, 64);
    __shared__ float c2p[8][16];
    if (q == 0) c2p[wv][l15] = s;

    // accumulator zeroing + optional fp32 codebook copy (independent of LDS above)
    const int base = g * 512 + t;          // 0 .. 32767
    if (base < nloss) lossR[base] = 0.f;
    if (base < zcount) probs_part[base] = 0.f;
    if (base + 32768 < zcount) probs_part[base + 32768] = 0.f;
    if (docopy) {
        #pragma unroll
        for (int i = 0; i < 8; i++) outcb[base + i * 32768] = cb[base + i * 32768];
    }

    __syncthreads();
    if (t < 16) {
        float acc = 0.f;
        #pragma unroll
        for (int ww = 0; ww < 8; ww++) acc += c2p[ww][t];
        c2[g * 16 + t] = acc;
    }
}

// ---------------- K1: fused distances + argmin + softmax + gather + loss ----------------
// 1024 threads (16 waves), 64 tokens/block, grid 1024. Wave w owns codes [64w, 64w+64).
// acc: 4 M-tiles x 4 N-tiles = 64 acc regs; each B fragment feeds 4 MFMAs (ratio 4:1).
// acc pre-initialized with -0.5*c2 so s = -2*acc directly. Argmin via packed uint keys.
__global__ __launch_bounds__(1024, 4) void k_main(const float* __restrict__ z,
                                                  const float* __restrict__ cb,
                                                  const unsigned short* __restrict__ cbf,
                                                  const float* __restrict__ c2,
                                                  float* __restrict__ out_q,
                                                  float* __restrict__ probs_part,
                                                  float* __restrict__ lossR,
                                                  int repmask) {
    const int t   = threadIdx.x;
    const int w   = t >> 6;       // wave 0..15
    const int ln  = t & 63;
    const int q   = ln >> 4;
    const int l15 = ln & 15;
    const int k0  = w * 64;
    const int n0  = blockIdx.x * TM;
    float* pp = probs_part + (blockIdx.x & repmask) * K_CODES;

    __shared__ unsigned short a_lds[32 * 64 * 8];   // 32 KB, frag f=(m*8+ds)*64+ln at a_lds[f*8]
    __shared__ float    z2p[32][16];                // z2 partials: [m*8+ds][row16]
    __shared__ unsigned kred[16][64];
    __shared__ float    ered[16][64];
    __shared__ int   fidx[64];
    __shared__ float fU[64];

    // ---- phase 0: cooperative A fill (fp32 -> bf16, fragment order) + z2 partials ----
    #pragma unroll
    for (int rep = 0; rep < 2; rep++) {
        const int f   = t + rep * 1024;
        const int md  = w + rep * 16;      // = m*8 + ds
        const int m   = md >> 3;
        const int dsv = md & 7;
        const int row = m * 16 + l15;
        const int dim = dsv * 32 + q * 8;
        const float* zp = z + (size_t)(n0 + row) * DIM + dim;
        f32x4 z0 = *(const f32x4*)(zp);
        f32x4 z1 = *(const f32x4*)(zp + 4);
        s16x8 a;
        a[0] = (short)f32_to_bf16(z0[0]); a[1] = (short)f32_to_bf16(z0[1]);
        a[2] = (short)f32_to_bf16(z0[2]); a[3] = (short)f32_to_bf16(z0[3]);
        a[4] = (short)f32_to_bf16(z1[0]); a[5] = (short)f32_to_bf16(z1[1]);
        a[6] = (short)f32_to_bf16(z1[2]); a[7] = (short)f32_to_bf16(z1[3]);
        *(s16x8*)(a_lds + (size_t)f * 8) = a;
        float s = z0[0]*z0[0] + z0[1]*z0[1] + z0[2]*z0[2] + z0[3]*z0[3]
                + z1[0]*z1[0] + z1[1]*z1[1] + z1[2]*z1[2] + z1[3]*z1[3];
        s += __shfl_xor(s, 16, 64);
        s += __shfl_xor(s, 32, 64);
        if (q == 0) z2p[md][l15] = s;      // no atomics, single writer
    }

    // acc init: -0.5*c2[col]  (then s = -2*acc after MFMA)
    float c2v[4];
    #pragma unroll
    for (int nt = 0; nt < 4; nt++) c2v[nt] = c2[k0 + nt * 16 + l15];
    f32x4 acc[4][4];
    #pragma unroll
    for (int m = 0; m < 4; m++)
        #pragma unroll
        for (int nt = 0; nt < 4; nt++) {
            const float iv = -0.5f * c2v[nt];
            f32x4 v4 = {iv, iv, iv, iv};
            acc[m][nt] = v4;
        }

    __syncthreads();

    // ---- K loop: 8 steps of 32 dims, 16 MFMA per 4 B-loads ----
    const unsigned short* bb = cbf + (size_t)(w * 4) * 8 * 1024 + ln * 8;
    #pragma unroll
    for (int ds = 0; ds < 8; ds++) {
        s16x8 af[4];
        #pragma unroll
        for (int m = 0; m < 4; m++)
            af[m] = *(const s16x8*)(a_lds + (size_t)((m * 8 + ds) * 64 + ln) * 8);
        #pragma unroll
        for (int nt = 0; nt < 4; nt++) {
            s16x8 b = *(const s16x8*)(bb + (size_t)(nt * 8 + ds) * 1024);
            #pragma unroll
            for (int m = 0; m < 4; m++)
                acc[m][nt] = __builtin_amdgcn_mfma_f32_16x16x32_bf16(af[m], b, acc[m][nt], 0, 0, 0);
        }
    }

    // ---- epilogue: packed-key argmax(acc) (= argmin s), expsum; e -> acc ----
    unsigned lkey[4][4];
    float    lesum[4][4];
    #pragma unroll
    for (int m = 0; m < 4; m++)
        #pragma unroll
        for (int v = 0; v < 4; v++) { lkey[m][v] = 0u; lesum[m][v] = 0.f; }

    #pragma unroll
    for (int m = 0; m < 4; m++)
        #pragma unroll
        for (int nt = 0; nt < 4; nt++) {
            const unsigned colc = 1023u - (unsigned)(k0 + nt * 16 + l15);  // complement: ties -> lowest col
            #pragma unroll
            for (int v = 0; v < 4; v++) {
                float a = acc[m][nt][v];
                unsigned key = (fkey(a) & 0xFFFFFC00u) | colc;
                lkey[m][v] = max(lkey[m][v], key);
                float e = __expf(a + a);          // exp(-s) = exp(2a)
                acc[m][nt][v] = e;
                lesum[m][v] += e;
            }
        }

    // cross-lane within quad group (16 lanes hold one row's 64-code slice)
    #pragma unroll
    for (int off = 1; off < 16; off <<= 1) {
        #pragma unroll
        for (int m = 0; m < 4; m++)
            #pragma unroll
            for (int v = 0; v < 4; v++) {
                unsigned ok = (unsigned)__shfl_xor((int)lkey[m][v], off, 64);
                float    oe = __shfl_xor(lesum[m][v], off, 64);
                lkey[m][v] = max(lkey[m][v], ok);
                lesum[m][v] += oe;
            }
    }

    // cross-wave combine (16 waves) through LDS
    if (l15 == 0) {
        #pragma unroll
        for (int m = 0; m < 4; m++)
            #pragma unroll
            for (int v = 0; v < 4; v++) {
                const int r = m * 16 + q * 4 + v;
                kred[w][r] = lkey[m][v]; ered[w][r] = lesum[m][v];
            }
    }
    __syncthreads();
    float lossreg = 0.f;
    if (t < 64) {
        unsigned bk = kred[0][t];
        float U = ered[0][t];
        #pragma unroll
        for (int ww = 1; ww < 16; ww++) {
            bk = max(bk, kred[ww][t]);
            U += ered[ww][t];
        }
        fidx[t] = 1023 - (int)(bk & 1023u);
        fU[t] = U;
        float a_rec = fkey_inv(bk);        // quantized a; s_min = -2a
        float z2 = 0.f;
        #pragma unroll
        for (int ds = 0; ds < 8; ds++) z2 += z2p[(t >> 4) * 8 + ds][t & 15];
        lossreg = z2 - 2.0f * a_rec;       // ||z-q||^2 = ||z||^2 + s_min
    }
    __syncthreads();

    // probs: column sums of e/U over the block's 64 rows
    float ps[4];
    #pragma unroll
    for (int nt = 0; nt < 4; nt++) ps[nt] = 0.f;
    #pragma unroll
    for (int m = 0; m < 4; m++)
        #pragma unroll
        for (int v = 0; v < 4; v++) {
            const float invU = 1.0f / fU[m * 16 + q * 4 + v];
            #pragma unroll
            for (int nt = 0; nt < 4; nt++) ps[nt] += acc[m][nt][v] * invU;
        }
    #pragma unroll
    for (int nt = 0; nt < 4; nt++) {
        ps[nt] += __shfl_xor(ps[nt], 16, 64);
        ps[nt] += __shfl_xor(ps[nt], 32, 64);
    }
    atomicAdd(&pp[k0 + q * 16 + l15], ps[q]);   // 1 atomic per lane

    // quantized gather + store: wave w handles rows [4w, 4w+4)
    #pragma unroll
    for (int i = 0; i < 4; i++) {
        const int r  = w * 4 + i;
        const int am = fidx[r];
        f32x4 qv = *(const f32x4*)(cb + (size_t)am * DIM + ln * 4);
        *(f32x4*)(out_q + (size_t)(n0 + r) * DIM + ln * 4) = qv;
    }

    // loss: one atomic per block, spread over 64 slots
    if (w == 0) {
        #pragma unroll
        for (int off = 32; off; off >>= 1) lossreg += __shfl_down(lossreg, off, 64);
        if (ln == 0) atomicAdd(&lossR[blockIdx.x & 63], lossreg);
    }
}

// ---------------- K2: (optional codebook copy), probs reduce+mean+clip, vq_loss ----------------
__global__ __launch_bounds__(256) void k_fin(const float* __restrict__ cb,
                                             const float* __restrict__ probs_part,
                                             const float* __restrict__ lossR,
                                             float* __restrict__ out,
                                             int R, int nLoss, int docopy) {
    const int g = blockIdx.x * 256 + threadIdx.x;
    if (docopy && g < 262144) out[CB_OFF + g] = cb[g];
    if (g < K_CODES) {
        float a0 = 0.f, a1 = 0.f, a2 = 0.f, a3 = 0.f;
        if (R >= 4) {
            for (int r = 0; r < R; r += 4) {
                a0 += probs_part[(r + 0) * K_CODES + g];
                a1 += probs_part[(r + 1) * K_CODES + g];
                a2 += probs_part[(r + 2) * K_CODES + g];
                a3 += probs_part[(r + 3) * K_CODES + g];
            }
        } else {
            for (int r = 0; r < R; r++) a0 += probs_part[r * K_CODES + g];
        }
        float p = (a0 + a1 + a2 + a3) * (1.0f / 65536.0f);
        p = fminf(fmaxf(p, 0.001f), 0.999f);
        out[PROBS_OFF + g] = p;
    }
    if (g == 0) {
        float ls = 0.f;
        for (int r = 0; r < nLoss; r++) ls += lossR[r];
        out[LOSS_OFF] = ls * (1280.0f / 16777216.0f);   // 1.25*1024/(65536*256)
    }
}

extern "C" void kernel_launch(void* const* d_in, const int* in_sizes, int n_in,
                              void* d_out, int out_size, void* d_ws, size_t ws_size,
                              hipStream_t stream) {
    (void)in_sizes; (void)n_in; (void)out_size;
    const float* z  = (const float*)d_in[0];
    const float* cb = (const float*)d_in[1];
    float* out = (float*)d_out;

    float* c2 = (float*)d_ws;                 // 1024 floats

    // probs replicas: R in {64,16,4} in ws, else fallback single accumulator in out.
    float *probs_part, *lossR;
    int R, nLoss;
    size_t used = 1024 * 4;
    auto fits = [&](int r) { return ws_size >= used + (size_t)(64 + r * 1024) * 4; };
    if      (fits(64)) R = 64;
    else if (fits(16)) R = 16;
    else if (fits(4))  R = 4;
    else               R = 0;
    if (R) {
        lossR      = c2 + 1024;
        probs_part = lossR + 64;
        nLoss = 64;
        used += (size_t)(64 + R * 1024) * 4;
    } else {
        probs_part = out + PROBS_OFF;
        lossR      = out + LOSS_OFF;
        R = 1; nLoss = 1;
    }

    // bf16 frag-layout codebook: ws if it fits (then k_prep writes the fp32 copy),
    // else in out's codebook region (then k_fin rewrites it with fp32).
    unsigned short* cbf;
    int cbf_in_ws = (ws_size >= used + (size_t)K_CODES * DIM * 2);
    if (cbf_in_ws) cbf = (unsigned short*)((char*)d_ws + used);
    else           cbf = (unsigned short*)(out + CB_OFF);

    k_prep<<<dim3(64), dim3(512), 0, stream>>>(cb, c2, cbf, probs_part, lossR,
                                               out + CB_OFF, R * 1024, nLoss, cbf_in_ws);
    k_main<<<dim3(N_TOK / TM), dim3(1024), 0, stream>>>(z, cb, cbf, c2, out, probs_part,
                                                        lossR, R - 1);
    const int fin_blocks = cbf_in_ws ? 4 : 1024;
    k_fin<<<dim3(fin_blocks), dim3(256), 0, stream>>>(cb, probs_part, lossR, out,
                                                      R, nLoss, !cbf_in_ws);
}